// Round 1
// 83.441 us; speedup vs baseline: 1.0665x; 1.0665x over previous
//
#include <hip/hip_runtime.h>
#include <math.h>

#define NB 32
#define NA 5
#define NC 8
#define NH 32
#define NW 64
#define NT 50
#define NCH (7 + NC)                 // 15 channels per anchor
#define HW (NH * NW)                 // 2048
#define OBJECT_SCALE 10.0f
#define BLOCKS_PER_B ((NA * HW) / 256)   // 40

__constant__ float c_anchors[NA * 2] = {
    1.08f, 1.19f, 3.42f, 4.41f, 6.63f, 11.38f, 9.42f, 5.11f, 16.62f, 10.52f};

__device__ __forceinline__ float fast_exp(float v) { return __expf(v); }
__device__ __forceinline__ float fast_log(float v) { return __logf(v); }
__device__ __forceinline__ float fast_sigmoid(float v) {
    return __builtin_amdgcn_rcpf(1.0f + __expf(-v));
}

// ---------------------------------------------------------------------------
// Fused kernel: wave 0 of each block recomputes the 50 per-target records for
// its batch b directly into LDS (~60 VALU ops, redundant across the 40 blocks
// of the same b but far cheaper than a separate kernel launch + global
// round-trip). Then one thread per cell (b,a,j,i) runs the silence/assign loop
// against the LDS records (same-address broadcast reads, conflict-free).
//
// Record layout (identical semantics to the old prep_kernel):
//  sA[t]: [tlx, thx, tly, thy, ct2=0.375*area, code, -, -]   (hot, every iter)
//  sB[t]: [tx, ty, im, re, cls, tw_log, tl_log, area]        (cold, obj cells)
// ---------------------------------------------------------------------------
__global__ __launch_bounds__(256) void fused_kernel(const float* __restrict__ output,
                                                    const float* __restrict__ target,
                                                    float* __restrict__ out) {
    __shared__ __align__(16) float sA[NT * 8];
    __shared__ __align__(16) float sB[NT * 8];
    __shared__ int s_nv;
    __shared__ float s_part[4];

    int b = blockIdx.x / BLOCKS_PER_B;

    if (threadIdx.x < 64) {
        int t = threadIdx.x;
        const float* tp = target + (size_t)(b * NT + t) * 7;
        float t0 = 0.f, t1 = 0.f, t2 = 0.f, t3 = 0.f, t4 = 0.f, t5 = 0.f, t6 = 0.f;
        if (t < NT) {
            t0 = tp[0]; t1 = tp[1]; t2 = tp[2]; t3 = tp[3];
            t4 = tp[4]; t5 = tp[5]; t6 = tp[6];
        }
        // validity = cumprod(tgt[...,1] != 0): monotone prefix -> trailing-ones
        unsigned long long bal = __ballot(t < NT && t1 != 0.0f);
        if (t == 0) s_nv = __ffsll((unsigned long long)~bal) - 1;

        if (t < NT) {
            float gx = t1 * (float)NW;
            float gy = t2 * (float)NH;
            float gw = t3 * (float)NW;
            float gl = t4 * (float)NH;

            // argmax anchor IoU (co-centered); strict > keeps first max
            int best_n = 0;
            float best = -1.0f;
#pragma unroll
            for (int aa = 0; aa < NA; ++aa) {
                float aw = c_anchors[2 * aa], al = c_anchors[2 * aa + 1];
                float inter = fminf(gw, aw) * fminf(gl, al);
                float uni = gw * gl + aw * al - inter;
                float iou = inter / uni;
                if (iou > best) { best = iou; best_n = aa; }
            }
            float aw = c_anchors[2 * best_n], al = c_anchors[2 * best_n + 1];

            int gi = min(max((int)gx, 0), NW - 1);   // trunc like astype(int32)
            int gj = min(max((int)gy, 0), NH - 1);

            float area = gw * gl;
            float* a8 = sA + t * 8;
            a8[0] = gx - gw * 0.5f;
            a8[1] = gx + gw * 0.5f;
            a8[2] = gy - gl * 0.5f;
            a8[3] = gy + gl * 0.5f;
            a8[4] = 0.375f * area;                              // 0.6/1.6
            a8[5] = (float)((best_n << 12) | (gj << 6) | gi);   // < 2^15, exact

            float* b8 = sB + t * 8;
            b8[0] = gx - (float)gi;
            b8[1] = gy - (float)gj;
            b8[2] = t5;
            b8[3] = t6;
            b8[4] = t0;
            b8[5] = fast_log(gw / aw);
            b8[6] = fast_log(gl / al);
            b8[7] = area;
        }
    }
    __syncthreads();

    int m = (blockIdx.x % BLOCKS_PER_B) * 256 + threadIdx.x;
    int a = m >> 11;          // / HW (uniform per block: 256 | 2048)
    int rem = m & (HW - 1);
    int j = rem >> 6;
    int i = rem & (NW - 1);

    // 5 always-needed channel loads, each coalesced (wave = one full i-row)
    const float* op = output + (size_t)(b * NA + a) * NCH * HW + (j << 6) + i;
    float o0 = op[0 * HW], o1 = op[1 * HW], o2 = op[2 * HW], o3 = op[3 * HW];
    float o6 = op[6 * HW];

    float x = fast_sigmoid(o0);
    float y = fast_sigmoid(o1);
    float conf = fast_sigmoid(o6);

    float aw = c_anchors[2 * a], al = c_anchors[2 * a + 1];
    float pbx = x + (float)i;
    float pby = y + (float)j;
    float pbw = fast_exp(o2) * aw;
    float pbl = fast_exp(o3) * al;

    float plx = pbx - pbw * 0.5f;
    float phx = pbx + pbw * 0.5f;
    float ply = pby - pbl * 0.5f;
    float phy = pby + pbl * 0.5f;
    float parea = pbw * pbl;
    float mycode = (float)((a << 12) | (j << 6) | i);

    int nv = s_nv;

    // silm = max_t(inter - 0.375*tarea); silenced <=> silm > 0.375*parea
    float silm = -1e30f;
    int ta = -1;          // last matching valid t == segment_max semantics
#pragma unroll 4
    for (int t = 0; t < nv; ++t) {
        float4 r0 = *reinterpret_cast<const float4*>(sA + (t << 3));      // ds_read_b128
        float2 r1 = *reinterpret_cast<const float2*>(sA + (t << 3) + 4);  // ds_read_b64
        float cw = fminf(r0.y, phx) - fmaxf(r0.x, plx);
        float ch = fminf(r0.w, phy) - fmaxf(r0.z, ply);
        float cwc = fmaxf(cw, 0.0f);
        float chc = fmaxf(ch, 0.0f);
        silm = fmaxf(silm, __builtin_fmaf(cwc, chc, -r1.x));
        if (r1.y == mycode) ta = t;
    }

    float loss;
    if (ta >= 0) {
        const float* ai = sA + (ta << 3);
        const float* bi = sB + (ta << 3);
        float tlx = ai[0], thx = ai[1], tly = ai[2], thy = ai[3];
        float tarea = bi[7];
        // tconf = IoU(gt, pred) — rare path, exact division
        float cw = fminf(thx, phx) - fmaxf(tlx, plx);
        float ch = fminf(thy, phy) - fmaxf(tly, ply);
        float inter = fmaxf(cw, 0.0f) * fmaxf(ch, 0.0f);
        float tconf = inter / (tarea + parea - inter);

        float o4 = op[4 * HW], o5 = op[5 * HW];
        float dx = x - bi[0];
        float dy = y - bi[1];
        float dw = o2 - bi[5];
        float dl = o3 - bi[6];
        float di = o4 - bi[2];
        float dr = o5 - bi[3];
        loss = dx * dx + dy * dy + dw * dw + dl * dl + di * di + dr * dr;

        float dc = OBJECT_SCALE * (conf - tconf);
        loss += dc * dc;

        // cross-entropy: logsumexp(logits) - logits[tcls]; lazy cls loads
        float cl[NC];
#pragma unroll
        for (int c = 0; c < NC; ++c) cl[c] = op[(size_t)(7 + c) * HW];
        int tcls = min(max((int)bi[4], 0), NC - 1);
        float mxl = cl[0];
#pragma unroll
        for (int c = 1; c < NC; ++c) mxl = fmaxf(mxl, cl[c]);
        float s = 0.0f;
#pragma unroll
        for (int c = 0; c < NC; ++c) s += fast_exp(cl[c] - mxl);
        loss += (mxl + fast_log(s)) - cl[tcls];
    } else {
        bool silenced = silm > 0.375f * parea;  // <=> max_iou > 0.6
        loss = silenced ? 0.0f : conf * conf;   // NOOBJECT_SCALE = 1
    }

    // wave (64) shuffle reduce, then cross-wave via LDS, one atomic per block
    for (int off = 32; off > 0; off >>= 1)
        loss += __shfl_down(loss, off, 64);
    int wave = threadIdx.x >> 6;
    int lane = threadIdx.x & 63;
    if (lane == 0) s_part[wave] = loss;
    __syncthreads();
    if (threadIdx.x == 0)
        atomicAdd(out, s_part[0] + s_part[1] + s_part[2] + s_part[3]);
}

extern "C" void kernel_launch(void* const* d_in, const int* in_sizes, int n_in,
                              void* d_out, int out_size, void* d_ws, size_t ws_size,
                              hipStream_t stream) {
    const float* output = (const float*)d_in[0];
    const float* target = (const float*)d_in[1];
    float* out = (float*)d_out;
    (void)d_ws; (void)ws_size;

    // out is re-poisoned by the harness each replay; zero it with a capturable
    // 4-byte memset node instead of a full prep-kernel dispatch.
    hipMemsetAsync(d_out, 0, sizeof(float), stream);
    hipLaunchKernelGGL(fused_kernel, dim3(NB * BLOCKS_PER_B), dim3(256), 0, stream,
                       output, target, out);
}